// Round 1
// baseline (5334.950 us; speedup 1.0000x reference)
//
#include <hip/hip_runtime.h>

#define DEVINL __device__ __forceinline__

namespace {
constexpr int B = 256, T = 128, F = 128, H = 512;
constexpr int NBLK = 256, NTHR = 1024;

// ---- workspace layout (4-byte words) ----
constexpr size_t OFF_NUM   = 0;                   // [128] loss numerators
constexpr size_t OFF_DEN   = 128;                 // [128] denominators
constexpr size_t OFF_CTR   = 256;                 // [64] group barrier counters (16 g x 3)
constexpr size_t OFF_WQF   = 320;                 // gate W i8 B-frags [mid16][nl8][kh2][lane64][24]
constexpr size_t OFF_FSCC  = OFF_WQF + 393216;    // [2048] cc dequant scale per col
constexpr size_t OFF_FSCHG = OFF_FSCC + 2048;     // [2048] h  dequant scale per col
constexpr size_t OFF_HISTQ = OFF_FSCHG + 2048;    // hist i8 [128 f][128 k4]
constexpr size_t OFF_FSCH  = OFF_HISTQ + 16384;   // [128]
constexpr size_t OFF_TD2   = OFF_FSCH + 128;      // td_h f16x2 [512 u][64]
constexpr size_t OFF_FEAT2 = OFF_TD2 + 32768;     // [128 f][64]
constexpr size_t OFF_WC2   = OFF_FEAT2 + 8192;    // [128 f][128]
constexpr size_t OFF_BSUM  = OFF_WC2 + 16384;     // [2048] b_ih+b_hh, col = 4*unit+gate
constexpr size_t OFF_FDIAG = OFF_BSUM + 2048;     // [128] f16-rounded feat diag
constexpr size_t OFF_HQB   = OFF_FDIAG + 128;     // [2][16 g][16 r][128] decayed-h i8x4
constexpr size_t OFF_XCB   = OFF_HQB + 65536;     // [2][16][16][64]  x_c f16x2
constexpr size_t OFF_CCB   = OFF_XCB + 32768;     // [2][16][16][32]  c_c i8x4
constexpr size_t WS_WORDS  = OFF_CCB + 16384;     // ~2.35 MB

constexpr float ACT_S  = 15.875f;
constexpr float DEQ_CC = 1.f / (127.f * 15.875f);
constexpr float DEQ_H  = 1.f / (127.f * 127.f);
}

typedef _Float16 h2_t __attribute__((ext_vector_type(2)));
typedef int v4i __attribute__((ext_vector_type(4)));

DEVINL h2_t as_h2(unsigned u) { union { unsigned u; h2_t h; } c; c.u = u; return c.h; }
DEVINL unsigned pack2(float a, float b) {
  union { h2_t h; unsigned u; } c;
  c.h = h2_t{(_Float16)a, (_Float16)b};
  return c.u;
}

#if defined(__has_builtin)
#if __has_builtin(__builtin_amdgcn_fdot2)
#define HAVE_FDOT2 1
#endif
#if __has_builtin(__builtin_amdgcn_sdot4)
#define HAVE_SDOT4 1
#endif
#endif
#ifdef HAVE_FDOT2
DEVINL float fdot2(h2_t a, h2_t b, float c) { return __builtin_amdgcn_fdot2(a, b, c, false); }
#else
DEVINL float fdot2(h2_t a, h2_t b, float c) {
  return fmaf((float)a.x, (float)b.x, fmaf((float)a.y, (float)b.y, c));
}
#endif
#ifdef HAVE_SDOT4
DEVINL int sdot4(int a, int b, int c) { return __builtin_amdgcn_sdot4(a, b, c, false); }
#else
DEVINL int sdot4(int a, int b, int c) {
  return c + ((a << 24) >> 24) * ((b << 24) >> 24)
           + ((a << 16) >> 24) * ((b << 16) >> 24)
           + ((a << 8) >> 24) * ((b << 8) >> 24)
           + (a >> 24) * (b >> 24);
}
#endif

DEVINL float fast_sig(float x)  { return 1.f / (1.f + __expf(-x)); }
DEVINL float fast_tanh(float x) { return 1.f - 2.f / (1.f + __expf(2.f * x)); }

DEVINL float wave_sum(float v) {
#pragma unroll
  for (int s = 32; s; s >>= 1) v += __shfl_down(v, s, 64);
  return v;
}
DEVINL float wave_max(float v) {
#pragma unroll
  for (int s = 32; s; s >>= 1) v = fmaxf(v, __shfl_down(v, s, 64));
  return v;
}

// device-coherent (cross-XCD safe) accesses for group exchange buffers
DEVINL unsigned agload(const unsigned* p) {
  return __hip_atomic_load(p, __ATOMIC_RELAXED, __HIP_MEMORY_SCOPE_AGENT);
}
DEVINL unsigned long long agload64(const unsigned long long* p) {
  return __hip_atomic_load(p, __ATOMIC_RELAXED, __HIP_MEMORY_SCOPE_AGENT);
}
DEVINL void agstore(unsigned* p, unsigned v) {
  __hip_atomic_store(p, v, __ATOMIC_RELAXED, __HIP_MEMORY_SCOPE_AGENT);
}

// monotone group barrier: each of 16 member blocks adds 1; wait for target.
DEVINL void group_barrier(unsigned* ctr, unsigned target) {
  __syncthreads();   // drains each thread's outstanding global stores (vmcnt 0)
  if (threadIdx.x == 0) {
    __threadfence();
    __hip_atomic_fetch_add(ctr, 1u, __ATOMIC_RELEASE, __HIP_MEMORY_SCOPE_AGENT);
    unsigned v = __hip_atomic_load(ctr, __ATOMIC_ACQUIRE, __HIP_MEMORY_SCOPE_AGENT);
    int guard = 0;
    while (v < target && ++guard < (1 << 24)) {
      __builtin_amdgcn_s_sleep(1);
      v = __hip_atomic_load(ctr, __ATOMIC_ACQUIRE, __HIP_MEMORY_SCOPE_AGENT);
    }
  }
  __syncthreads();
}

// ---- prep: f16 tables (frag-friendly layouts) + biases ----
__global__ void prep_f16(const float* __restrict__ td_h_W, const float* __restrict__ feat_W,
                         const float* __restrict__ wc_W, const float* __restrict__ b_ih,
                         const float* __restrict__ b_hh,
                         unsigned* __restrict__ wsu, float* __restrict__ wsf) {
  const int idx = blockIdx.x * blockDim.x + threadIdx.x;
  if (idx < 32768) {                           // TD2 [512 u][64 k2]
    const int u = idx >> 6, k2 = idx & 63;
    wsu[OFF_TD2 + idx] = pack2(td_h_W[u * 128 + 2 * k2], td_h_W[u * 128 + 2 * k2 + 1]);
  } else if (idx < 40960) {                    // FEAT2 [128 f][64]
    const int i = idx - 32768, f = i >> 6, k2 = i & 63;
    wsu[OFF_FEAT2 + i] = pack2(feat_W[f * 128 + 2 * k2], feat_W[f * 128 + 2 * k2 + 1]);
  } else if (idx < 57344) {                    // WC2 [128 f][128]
    const int i = idx - 40960, f = i >> 7, k2 = i & 127;
    wsu[OFF_WC2 + i] = pack2(wc_W[f * 256 + 2 * k2], wc_W[f * 256 + 2 * k2 + 1]);
  } else if (idx < 59392) {                    // BSUM [2048]
    const int i = idx - 57344, unit = i >> 2, g = i & 3;
    wsf[OFF_BSUM + i] = b_ih[g * 512 + unit] + b_hh[g * 512 + unit];
  } else if (idx < 59520) {                    // FDIAG [128]
    const int f = idx - 59392;
    wsf[OFF_FDIAG + f] = (float)(_Float16)feat_W[f * 129];
  }
}

DEVINL unsigned q4pack(float4 v, float s) {
  const int q0 = __float2int_rn(v.x * s), q1 = __float2int_rn(v.y * s);
  const int q2 = __float2int_rn(v.z * s), q3 = __float2int_rn(v.w * s);
  return (q0 & 0xFF) | ((q1 & 0xFF) << 8) | ((q2 & 0xFF) << 16) | ((q3 & 0xFF) << 24);
}

// ---- prep: i8 quant of gate weights into MFMA B-fragment order ----
// B-frag for tile (ntile,ktile): lane l holds col = ntile*16+(l&15),
// k bytes = ktile*64 + (l>>4)*16 + reg*4 + {0..3}  (= dword k4 = ktile*16+(l>>4)*4+reg)
__global__ void prep_gates(const float* __restrict__ Wih, const float* __restrict__ Whh,
                           unsigned* __restrict__ wsu, float* __restrict__ wsf) {
  const int col = blockIdx.x;                  // 2048 = 4*unit+gate
  const int unit = col >> 2, g = col & 3, t = threadIdx.x;   // 64 threads
  const float* si = Wih + (size_t)(g * 512 + unit) * 256;
  const float* sh = Whh + (size_t)(g * 512 + unit) * 512;
  const float4 vi = ((const float4*)si)[t];
  const float4 va = ((const float4*)sh)[t];
  const float4 vb = ((const float4*)sh)[t + 64];
  float mi = fmaxf(fmaxf(fabsf(vi.x), fabsf(vi.y)), fmaxf(fabsf(vi.z), fabsf(vi.w)));
  float mh = fmaxf(fmaxf(fmaxf(fabsf(va.x), fabsf(va.y)), fmaxf(fabsf(va.z), fabsf(va.w))),
                   fmaxf(fmaxf(fabsf(vb.x), fabsf(vb.y)), fmaxf(fabsf(vb.z), fabsf(vb.w))));
  mi = wave_max(mi); mh = wave_max(mh);
  mi = __shfl(mi, 0, 64); mh = __shfl(mh, 0, 64);
  const float ssi = (mi > 0.f) ? 127.f / mi : 0.f;
  const float ssh = (mh > 0.f) ? 127.f / mh : 0.f;
  if (t == 0) { wsf[OFF_FSCC + col] = mi * DEQ_CC; wsf[OFF_FSCHG + col] = mh * DEQ_H; }

  const int mid = col >> 7, nl = (col >> 4) & 7, c15 = col & 15;
  const int q = (t >> 2) & 3, r = t & 3;
  {  // cc part, dword k4 = t (0..63)
    const int kt = t >> 4, kh = kt >> 1, loc = (kt & 1) * 4 + r;
    const size_t a = ((size_t)((((mid * 8 + nl) * 2 + kh) * 64) + q * 16 + c15)) * 24 + loc;
    wsu[OFF_WQF + a] = q4pack(vi, ssi);
  }
#pragma unroll
  for (int p = 0; p < 2; ++p) {  // h part, dword k4 = t + 64p (0..127)
    const int k4 = t + 64 * p;
    const int kt = k4 >> 4, kh = kt >> 2, loc = 8 + (kt & 3) * 4 + r;
    const size_t a = ((size_t)((((mid * 8 + nl) * 2 + kh) * 64) + q * 16 + c15)) * 24 + loc;
    wsu[OFF_WQF + a] = q4pack(p ? vb : va, ssh);
  }
}

// ---- prep: i8 quant of hist_W rows, [f][k4] layout ----
__global__ void prep_hist(const float* __restrict__ histW,
                          unsigned* __restrict__ wsu, float* __restrict__ wsf) {
  const int f = blockIdx.x;                    // 128
  const float* src = histW + (size_t)f * 512;
  const int t = threadIdx.x;                   // 128 threads
  const float4 v = ((const float4*)src)[t];
  float mx = fmaxf(fmaxf(fabsf(v.x), fabsf(v.y)), fmaxf(fabsf(v.z), fabsf(v.w)));
  mx = wave_max(mx);
  __shared__ float wm[2];
  if ((t & 63) == 0) wm[t >> 6] = mx;
  __syncthreads();
  const float maxv = fmaxf(wm[0], wm[1]);
  const float s = (maxv > 0.f) ? 127.f / maxv : 0.f;
  wsu[OFF_HISTQ + (size_t)f * 128 + t] = q4pack(v, s);
  if (t == 0) wsf[OFF_FSCH + f] = maxv * DEQ_H;
}

// ---- main: 16 groups x 16 blocks; group = 16 rows; member owns 32 units,
//      128 gate cols (8 MFMA n-tiles, B-frags persistent in VGPRs), 8 features ----
__global__ void __launch_bounds__(NTHR) rits_group(
    const float* __restrict__ x, const float* __restrict__ m, const float* __restrict__ d,
    const float* __restrict__ tx, const float* __restrict__ tmask,
    const float* __restrict__ td_h_b, const float* __restrict__ td_x_W,
    const float* __restrict__ td_x_b, const float* __restrict__ hist_b,
    const float* __restrict__ feat_b, const float* __restrict__ wc_b,
    unsigned* __restrict__ ws, const float* __restrict__ wsf,
    float* __restrict__ num, float* __restrict__ den, float* __restrict__ out)
{
  const int tid = threadIdx.x;
  const int grp = blockIdx.x & 15, mid = blockIdx.x >> 4;
  const int r0g = grp << 4, u0 = mid << 5, f0 = mid << 3, c0 = mid << 7;
  const int lane = tid & 63, wv = tid >> 6;
  const int nl = wv >> 1, kh = wv & 1;
  const int m15 = lane & 15, lg = lane >> 4, swA = (m15 & 3) << 2;

  // persistent LDS tables (staged once) + per-step working buffers
  __shared__ __align__(16) unsigned tdl_s[32 * 68];    // td slice [u][64]+pad
  __shared__ __align__(16) unsigned histl_s[8 * 132];  // hist slice [f][128]+pad
  __shared__ __align__(16) unsigned featl_s[8 * 68];
  __shared__ __align__(16) unsigned wcl_s[8 * 132];
  __shared__ __align__(16) unsigned hq_s[16 * 132];    // gathered decayed-h i8 (swizzled)
  __shared__ __align__(16) unsigned actq_s[16 * 68];   // cc|m i8 (swizzled)
  __shared__ float h_s[16 * 33], c_s[16 * 33];         // recurrent state [r][u_local]
  __shared__ float dxw_s[128], dxb_s[128];
  __shared__ __align__(16) unsigned arena32[4800];     // overlaid buffers (see below)

  unsigned* d2_a   = arena32;                 // [16][68]  d f16 pairs
  unsigned* xc2_a  = arena32 + 1088;          // [16][68]  gathered x_c pairs
  unsigned* gxm2_a = arena32 + 2176;          // [16][132] gx pairs | m pairs
  float* xsl  = (float*)(arena32 + 4288);     // [16][8] x slice
  float* txsl = (float*)(arena32 + 4416);
  float* evsl = (float*)(arena32 + 4544);
  float* msl  = (float*)(arena32 + 4672);
  float* gb   = (float*)arena32;              // [2 kh][128 col][18] gate partials (post-B3 only)

  // persistent gate-weight B-fragments: 24 VGPRs
  const unsigned* wqf = ws + OFF_WQF +
      (size_t)((((mid << 3) + nl) * 2 + kh) * 64 + lane) * 24;
  const v4i bcc0 = *(const v4i*)(wqf + 0),  bcc1 = *(const v4i*)(wqf + 4);
  const v4i bh0  = *(const v4i*)(wqf + 8),  bh1  = *(const v4i*)(wqf + 12);
  const v4i bh2  = *(const v4i*)(wqf + 16), bh3  = *(const v4i*)(wqf + 20);

  const int colg = c0 + (nl << 4) + m15;
  const float fscc_r = wsf[OFF_FSCC + colg];
  const float fsch_r = wsf[OFF_FSCHG + colg];
  const float bs_r   = wsf[OFF_BSUM + colg];

  float tdb = 0.f;
  if (tid < 512) tdb = td_h_b[u0 + (tid >> 4)];
  float hb = 0.f, fb = 0.f, wb = 0.f, fd = 0.f, fsf = 0.f;
  if (tid < 128) {
    const int f = f0 + (tid & 7);
    hb = hist_b[f]; fb = feat_b[f]; wb = wc_b[f];
    fd = wsf[OFF_FDIAG + f]; fsf = wsf[OFF_FSCH + f];
  }

  // stage persistent tables
  {
    if (tid < 512) {
      const int u = tid >> 4, w4 = (tid & 15) << 2;
#pragma unroll
      for (int i = 0; i < 4; ++i)
        tdl_s[u * 68 + w4 + i] = ws[OFF_TD2 + (size_t)(u0 + u) * 64 + w4 + i];
      featl_s[(tid >> 6) * 68 + (tid & 63)] =
          ws[OFF_FEAT2 + (size_t)(f0 + (tid >> 6)) * 64 + (tid & 63)];
    }
    histl_s[(tid >> 7) * 132 + (tid & 127)] =
        ws[OFF_HISTQ + (size_t)(f0 + (tid >> 7)) * 128 + (tid & 127)];
    wcl_s[(tid >> 7) * 132 + (tid & 127)] =
        ws[OFF_WC2 + (size_t)(f0 + (tid >> 7)) * 128 + (tid & 127)];
    if (tid < 128) { dxw_s[tid] = td_x_W[tid * 129]; dxb_s[tid] = td_x_b[tid]; }
    if (tid < 528) { h_s[tid] = 0.f; c_s[tid] = 0.f; }
  }
  __syncthreads();

  unsigned* ctr = ws + OFF_CTR + grp * 3;

  for (int t = 0; t < T; ++t) {
    const int par = t & 1;
    unsigned* hqb = ws + OFF_HQB + (size_t)((par * 16 + grp) * 16) * 128;
    unsigned* xcb = ws + OFF_XCB + (size_t)((par * 16 + grp) * 16) * 64;
    unsigned* ccb = ws + OFF_CCB + (size_t)((par * 16 + grp) * 16) * 32;
    const unsigned tgt = 16u * (unsigned)(t + 1);

    float xh = 0.f, xc = 0.f, mvv = 0.f, xvv = 0.f;   // live on tid<128

    // ---- STAGE: inputs for the group's 16 rows ----
    {
      const int r = tid >> 6, j = tid & 63;
      const size_t base = ((size_t)(r0g + r) * T + t) * F;
      const float dv0 = d[base + 2 * j], dv1 = d[base + 2 * j + 1];
      d2_a[r * 68 + j] = pack2(dv0, dv1);
      const float gx0 = __expf(-fmaxf(fmaf(dv0, dxw_s[2 * j], dxb_s[2 * j]), 0.f));
      const float gx1 = __expf(-fmaxf(fmaf(dv1, dxw_s[2 * j + 1], dxb_s[2 * j + 1]), 0.f));
      gxm2_a[r * 132 + j] = pack2(gx0, gx1);
      const float mv0 = m[base + 2 * j], mv1 = m[base + 2 * j + 1];
      gxm2_a[r * 132 + 64 + j] = pack2(mv0, mv1);
      if (j < 32) {
        const int q0 = __float2int_rn(m[base + 4 * j] * ACT_S);
        const int q1 = __float2int_rn(m[base + 4 * j + 1] * ACT_S);
        const int q2 = __float2int_rn(m[base + 4 * j + 2] * ACT_S);
        const int q3 = __float2int_rn(m[base + 4 * j + 3] * ACT_S);
        actq_s[r * 68 + ((32 + j) ^ ((r & 3) << 2))] =
            (q0 & 0xFF) | ((q1 & 0xFF) << 8) | ((q2 & 0xFF) << 16) | ((q3 & 0xFF) << 24);
        const int k = j & 7, sel = j >> 3;
        const float v = (sel == 0) ? x[base + f0 + k] : (sel == 1) ? tx[base + f0 + k]
                      : (sel == 2) ? tmask[base + f0 + k] : m[base + f0 + k];
        if (sel == 0) xsl[r * 8 + k] = v;
        else if (sel == 1) txsl[r * 8 + k] = v;
        else if (sel == 2) evsl[r * 8 + k] = v;
        else msl[r * 8 + k] = v;
      }
    }
    __syncthreads();   // S1

    // ---- GAMMA_H: decay local h slice, quantize, publish ----
    if (tid < 512) {
      const int u = tid >> 4, r = tid & 15;
      float g0 = tdb;
      const uint4* tw = (const uint4*)(tdl_s + u * 68);
      const uint4* dw = (const uint4*)(d2_a + r * 68);
#pragma unroll
      for (int q = 0; q < 16; ++q) {
        const uint4 w = tw[q], dd = dw[q];
        g0 = fdot2(as_h2(w.x), as_h2(dd.x), g0);
        g0 = fdot2(as_h2(w.y), as_h2(dd.y), g0);
        g0 = fdot2(as_h2(w.z), as_h2(dd.z), g0);
        g0 = fdot2(as_h2(w.w), as_h2(dd.w), g0);
      }
      const float hv = h_s[r * 33 + u] * __expf(-fmaxf(g0, 0.f));
      h_s[r * 33 + u] = hv;
      int q = __float2int_rn(hv * 127.f);
      const int a1 = __shfl_down(q, 16, 64), a2 = __shfl_down(q, 32, 64),
                a3 = __shfl_down(q, 48, 64);
      if (!(u & 3))
        agstore(hqb + r * 128 + (u0 >> 2) + (u >> 2),
                (q & 0xFF) | ((a1 & 0xFF) << 8) | ((a2 & 0xFF) << 16) | ((a3 & 0xFF) << 24));
    }
    group_barrier(ctr + 0, tgt);   // B1

    // ---- gather full decayed-h (swizzled for MFMA A-frags) ----
    {
      const int r = tid >> 6, w0 = (tid & 63) << 1;
      const unsigned long long v =
          agload64((const unsigned long long*)(hqb + r * 128 + w0));
      const int swr = (r & 3) << 2;
      hq_s[r * 132 + (w0 ^ swr)] = (unsigned)v;
      hq_s[r * 132 + ((w0 | 1) ^ swr)] = (unsigned)(v >> 32);
    }
    __syncthreads();   // S2

    // ---- X_HIST + X_C (8 features x 16 rows), publish x_c pairs ----
    if (tid < 128) {
      const int r = tid >> 3, fl = tid & 7;
      int isum = 0;
      const uint4* hw = (const uint4*)(histl_s + fl * 132);
      const int swr = (r & 3) << 2;
#pragma unroll 8
      for (int qq = 0; qq < 32; ++qq) {
        const uint4 w = hw[qq];
        const int4 hv = *(const int4*)(hq_s + r * 132 + (((qq) << 2) ^ swr));
        isum = sdot4((int)w.x, hv.x, isum);
        isum = sdot4((int)w.y, hv.y, isum);
        isum = sdot4((int)w.z, hv.z, isum);
        isum = sdot4((int)w.w, hv.w, isum);
      }
      xh = fmaf((float)isum, fsf, hb);
      mvv = msl[r * 8 + fl]; xvv = xsl[r * 8 + fl];
      xc = mvv * xvv + (1.f - mvv) * xh;
      const float xcs = __shfl_down(xc, 1, 64);
      if (!(fl & 1)) agstore(xcb + r * 64 + ((f0 + fl) >> 1), pack2(xc, xcs));
    }
    group_barrier(ctr + 1, tgt);   // B2

    // ---- gather full x_c ----
    {
      const int r = tid >> 6, w = tid & 63;
      xc2_a[r * 68 + w] = agload(xcb + r * 64 + w);
    }
    __syncthreads();   // S3

    // ---- FEAT + ALPHA + C_H + C_C + OUT + LOSS, publish c_c i8 ----
    if (tid < 128) {
      const int r = tid >> 3, fl = tid & 7;
      float z = fb, aa = wb;
      {
        const uint4* fw = (const uint4*)(featl_s + fl * 68);
        const uint4* xw = (const uint4*)(xc2_a + r * 68);
#pragma unroll 8
        for (int qq = 0; qq < 16; ++qq) {
          const uint4 w = fw[qq], x4 = xw[qq];
          z = fdot2(as_h2(w.x), as_h2(x4.x), z);
          z = fdot2(as_h2(w.y), as_h2(x4.y), z);
          z = fdot2(as_h2(w.z), as_h2(x4.z), z);
          z = fdot2(as_h2(w.w), as_h2(x4.w), z);
        }
        const uint4* ww = (const uint4*)(wcl_s + fl * 132);
        const uint4* gw = (const uint4*)(gxm2_a + r * 132);
#pragma unroll 8
        for (int qq = 0; qq < 32; ++qq) {
          const uint4 w = ww[qq], g4 = gw[qq];
          aa = fdot2(as_h2(w.x), as_h2(g4.x), aa);
          aa = fdot2(as_h2(w.y), as_h2(g4.y), aa);
          aa = fdot2(as_h2(w.z), as_h2(g4.z), aa);
          aa = fdot2(as_h2(w.w), as_h2(g4.w), aa);
        }
      }
      z -= xc * fd;                            // remove diagonal
      const float al = fast_sig(aa);
      const float ch = al * z + (1.f - al) * xh;
      const float cc = mvv * xvv + (1.f - mvv) * ch;
      out[((size_t)(r0g + r) * T + t) * F + f0 + fl] = cc;
      const float tg = txsl[r * 8 + fl], evv = evsl[r * 8 + fl];
      const float e1 = xh - tg, e2 = z - tg, e3 = ch - tg;
      const float s1 = wave_sum(evv * (e1 * e1 + e2 * e2 + e3 * e3));
      const float s2 = wave_sum(evv);
      if (!(tid & 63)) { atomicAdd(&num[t], s1); atomicAdd(&den[t], s2); }
      int qc = __float2int_rn(fminf(fmaxf(cc, -8.f), 8.f) * ACT_S);
      const int c1 = __shfl_down(qc, 1, 64), c2 = __shfl_down(qc, 2, 64),
                c3 = __shfl_down(qc, 3, 64);
      if (!(fl & 3))
        agstore(ccb + r * 32 + ((f0 + fl) >> 2),
                (qc & 0xFF) | ((c1 & 0xFF) << 8) | ((c2 & 0xFF) << 16) | ((c3 & 0xFF) << 24));
    }

    // ---- GATES h-part (K=512): overlaps with feat waves; hq_s stable ----
    v4i accH = {0, 0, 0, 0};
    {
      const unsigned* hrow = hq_s + m15 * 132;
      const v4i a0 = *(const v4i*)(hrow + ((((kh * 4 + 0) << 4) + (lg << 2)) ^ swA));
      accH = __builtin_amdgcn_mfma_i32_16x16x64_i8(a0, bh0, accH, 0, 0, 0);
      const v4i a1 = *(const v4i*)(hrow + ((((kh * 4 + 1) << 4) + (lg << 2)) ^ swA));
      accH = __builtin_amdgcn_mfma_i32_16x16x64_i8(a1, bh1, accH, 0, 0, 0);
      const v4i a2 = *(const v4i*)(hrow + ((((kh * 4 + 2) << 4) + (lg << 2)) ^ swA));
      accH = __builtin_amdgcn_mfma_i32_16x16x64_i8(a2, bh2, accH, 0, 0, 0);
      const v4i a3 = *(const v4i*)(hrow + ((((kh * 4 + 3) << 4) + (lg << 2)) ^ swA));
      accH = __builtin_amdgcn_mfma_i32_16x16x64_i8(a3, bh3, accH, 0, 0, 0);
    }
    group_barrier(ctr + 2, tgt);   // B3

    // ---- gather full c_c i8 into actq (words 0..31; m words staged earlier) ----
    if (tid < 512) {
      const int r = tid >> 5, w = tid & 31;
      actq_s[r * 68 + (w ^ ((r & 3) << 2))] = agload(ccb + r * 32 + w);
    }
    __syncthreads();   // S4

    // ---- GATES cc|m-part (K=256) + write float partials ----
    {
      v4i accC = {0, 0, 0, 0};
      const unsigned* arow = actq_s + m15 * 68;
      const v4i a0 = *(const v4i*)(arow + ((((kh * 2 + 0) << 4) + (lg << 2)) ^ swA));
      accC = __builtin_amdgcn_mfma_i32_16x16x64_i8(a0, bcc0, accC, 0, 0, 0);
      const v4i a1 = *(const v4i*)(arow + ((((kh * 2 + 1) << 4) + (lg << 2)) ^ swA));
      accC = __builtin_amdgcn_mfma_i32_16x16x64_i8(a1, bcc1, accC, 0, 0, 0);
      float* gbp = gb + (size_t)((kh << 7) + (nl << 4) + m15) * 18 + (lg << 2);
      const float badd = kh ? 0.f : bs_r;
      gbp[0] = fmaf(fscc_r, (float)accC[0], fmaf(fsch_r, (float)accH[0], badd));
      gbp[1] = fmaf(fscc_r, (float)accC[1], fmaf(fsch_r, (float)accH[1], badd));
      gbp[2] = fmaf(fscc_r, (float)accC[2], fmaf(fsch_r, (float)accH[2], badd));
      gbp[3] = fmaf(fscc_r, (float)accC[3], fmaf(fsch_r, (float)accH[3], badd));
    }
    __syncthreads();   // S5

    // ---- LSTM update on local (unit,row) slice ----
    if (tid < 512) {
      const int ul = tid >> 4, r = tid & 15;
      float a4[4];
#pragma unroll
      for (int gg = 0; gg < 4; ++gg) {
        const int cl = ul * 4 + gg;
        a4[gg] = gb[(size_t)cl * 18 + r] + gb[(size_t)(128 + cl) * 18 + r];
      }
      const float ig = fast_sig(a4[0]), fg = fast_sig(a4[1]);
      const float g2 = fast_tanh(a4[2]), og = fast_sig(a4[3]);
      const float cv = fg * c_s[r * 33 + ul] + ig * g2;
      c_s[r * 33 + ul] = cv;
      h_s[r * 33 + ul] = og * fast_tanh(cv);
    }
    __syncthreads();   // S6: protect arena/actq for next step's stage
  }
}

__global__ void finalize(const float* __restrict__ num, const float* __restrict__ den,
                         float* __restrict__ out) {
  __shared__ float red[2];
  const int t = threadIdx.x;     // 128 threads
  float v = num[t] / (den[t] + 1e-8f);
  v = wave_sum(v);
  if ((t & 63) == 0) red[t >> 6] = v;
  __syncthreads();
  if (t == 0) out[(size_t)B * T * F] = (red[0] + red[1]) / (float)T;
}

extern "C" void kernel_launch(void* const* d_in, const int* in_sizes, int n_in,
                              void* d_out, int out_size, void* d_ws, size_t ws_size,
                              hipStream_t stream) {
  const float* x      = (const float*)d_in[0];
  const float* m      = (const float*)d_in[1];
  const float* d      = (const float*)d_in[2];
  const float* tx     = (const float*)d_in[3];
  const float* tmask  = (const float*)d_in[4];
  const float* td_h_W = (const float*)d_in[5];
  const float* td_h_b = (const float*)d_in[6];
  const float* td_x_W = (const float*)d_in[7];
  const float* td_x_b = (const float*)d_in[8];
  const float* hist_W = (const float*)d_in[9];
  const float* hist_b = (const float*)d_in[10];
  const float* feat_W = (const float*)d_in[11];
  const float* feat_b = (const float*)d_in[12];
  const float* wc_W   = (const float*)d_in[13];
  const float* wc_b   = (const float*)d_in[14];
  const float* W_ih   = (const float*)d_in[15];
  const float* W_hh   = (const float*)d_in[16];
  const float* b_ih   = (const float*)d_in[17];
  const float* b_hh   = (const float*)d_in[18];

  unsigned* wsu = (unsigned*)d_ws;
  float*    wsf = (float*)d_ws;
  float*    out = (float*)d_out;

  if (ws_size < WS_WORDS * 4) return;   // OOB tripwire

  hipMemsetAsync(d_ws, 0, (OFF_CTR + 64) * 4, stream);   // num/den + barrier counters
  prep_f16<<<dim3(233), dim3(256), 0, stream>>>(td_h_W, feat_W, wc_W, b_ih, b_hh, wsu, wsf);
  prep_gates<<<dim3(2048), dim3(64), 0, stream>>>(W_ih, W_hh, wsu, wsf);
  prep_hist<<<dim3(128), dim3(128), 0, stream>>>(hist_W, wsu, wsf);
  rits_group<<<dim3(NBLK), dim3(NTHR), 0, stream>>>(
      x, m, d, tx, tmask, td_h_b, td_x_W, td_x_b, hist_b, feat_b, wc_b,
      wsu, wsf, wsf + OFF_NUM, wsf + OFF_DEN, out);
  finalize<<<dim3(1), dim3(128), 0, stream>>>(wsf + OFF_NUM, wsf + OFF_DEN, out);
}

// Round 2
// 4240.759 us; speedup vs baseline: 1.2580x; 1.2580x over previous
//
#include <hip/hip_runtime.h>

#define DEVINL __device__ __forceinline__

namespace {
constexpr int B = 256, T = 128, F = 128, H = 512;
constexpr int NBLK = 256;        // 1 batch row per block
constexpr int NTHR = 1024;       // 16 waves

// workspace layout in 4-byte words
constexpr size_t OFF_NUM    = 0;                         // [128] loss numerators
constexpr size_t OFF_DEN    = 128;                       // [128] denominators
constexpr size_t OFF_WQCC   = 256;                       // gates cc|m i8x4 [64 k4][2048 col]
constexpr size_t OFF_WQH    = OFF_WQCC + 64 * 2048;      // gates h    i8x4 [128 k4][2048 col]
constexpr size_t OFF_FSCC   = OFF_WQH + 128 * 2048;      // [2048] colmax/(127*15.875)
constexpr size_t OFF_FSCHG  = OFF_FSCC + 2048;           // [2048] colmax/16129
constexpr size_t OFF_HISTQ  = OFF_FSCHG + 2048;          // hist i8x4 [128 f][128 k4] ROW-major
constexpr size_t OFF_FSCH   = OFF_HISTQ + 128 * 128;     // [128] colmax/16129
constexpr size_t OFF_TD2    = OFF_FSCH + 128;            // td_h f16x2 [512 u][64 k2] ROW-major
constexpr size_t OFF_FEAT2  = OFF_TD2 + 64 * 512;        // feat f16x2 [128 f][64 k2] ROW-major
constexpr size_t OFF_WC2    = OFF_FEAT2 + 64 * 128;      // wc   f16x2 [128 f][128 k2] ROW-major
constexpr size_t OFF_BSUM   = OFF_WC2 + 128 * 128;       // [2048] b_ih+b_hh gate-interleaved
constexpr size_t OFF_FDIAG  = OFF_BSUM + 2048;           // [128] f16-rounded feat diag
constexpr size_t WS_WORDS   = OFF_FDIAG + 128;           // ~1.81 MB

constexpr float ACT_S  = 15.875f;                // cc|m activation scale (clamp +-8)
constexpr float DEQ_CC = 1.f / (127.f * 15.875f);
constexpr float DEQ_H  = 1.f / (127.f * 127.f);
}

typedef _Float16 h2_t __attribute__((ext_vector_type(2)));

DEVINL h2_t as_h2(unsigned u) { union { unsigned u; h2_t h; } c; c.u = u; return c.h; }
DEVINL unsigned pack2(float a, float b) {
  union { h2_t h; unsigned u; } c;
  c.h = h2_t{(_Float16)a, (_Float16)b};
  return c.u;
}

#if defined(__has_builtin)
#if __has_builtin(__builtin_amdgcn_fdot2)
#define HAVE_FDOT2 1
#endif
#if __has_builtin(__builtin_amdgcn_sdot4)
#define HAVE_SDOT4 1
#endif
#endif
#ifdef HAVE_FDOT2
DEVINL float fdot2(h2_t a, h2_t b, float c) { return __builtin_amdgcn_fdot2(a, b, c, false); }
#else
DEVINL float fdot2(h2_t a, h2_t b, float c) {
  return fmaf((float)a.x, (float)b.x, fmaf((float)a.y, (float)b.y, c));
}
#endif
#ifdef HAVE_SDOT4
DEVINL int sdot4(int a, int b, int c) { return __builtin_amdgcn_sdot4(a, b, c, false); }
#else
DEVINL int sdot4(int a, int b, int c) {
  return c + ((a << 24) >> 24) * ((b << 24) >> 24)
           + ((a << 16) >> 24) * ((b << 16) >> 24)
           + ((a << 8) >> 24) * ((b << 8) >> 24)
           + (a >> 24) * (b >> 24);
}
#endif

DEVINL float fast_sig(float x)  { return 1.f / (1.f + __expf(-x)); }
DEVINL float fast_tanh(float x) { return 1.f - 2.f / (1.f + __expf(2.f * x)); }

DEVINL float wave_sum(float v) {
#pragma unroll
  for (int s = 32; s; s >>= 1) v += __shfl_down(v, s, 64);
  return v;
}
DEVINL float wave_max(float v) {
#pragma unroll
  for (int s = 32; s; s >>= 1) v = fmaxf(v, __shfl_down(v, s, 64));
  return v;
}

// ---- prep: f16 tables + biases (TD2 row-major, FEAT2/WC2 row-major) ----
__global__ void prep_f16(const float* __restrict__ td_h_W, const float* __restrict__ feat_W,
                         const float* __restrict__ wc_W, const float* __restrict__ b_ih,
                         const float* __restrict__ b_hh,
                         unsigned* __restrict__ wsu, float* __restrict__ wsf) {
  int idx = blockIdx.x * blockDim.x + threadIdx.x;
  if (idx < 32768) {                           // TD2 [512 u][64 k2]
    const int u = idx >> 6, k2 = idx & 63;
    wsu[OFF_TD2 + idx] = pack2(td_h_W[u * 128 + 2 * k2], td_h_W[u * 128 + 2 * k2 + 1]);
  } else if (idx < 40960) {                    // FEAT2 [128 f][64 k2]
    const int i = idx - 32768, f = i >> 6, k2 = i & 63;
    wsu[OFF_FEAT2 + i] = pack2(feat_W[f * 128 + 2 * k2], feat_W[f * 128 + 2 * k2 + 1]);
  } else if (idx < 57344) {                    // WC2 [128 f][128 k2]
    const int i = idx - 40960, f = i >> 7, k2 = i & 127;
    wsu[OFF_WC2 + i] = pack2(wc_W[f * 256 + 2 * k2], wc_W[f * 256 + 2 * k2 + 1]);
  } else if (idx < 59392) {                    // BSUM [2048]
    const int i = idx - 57344, unit = i >> 2, g = i & 3;
    wsf[OFF_BSUM + i] = b_ih[g * 512 + unit] + b_hh[g * 512 + unit];
  } else if (idx < 59520) {                    // FDIAG [128]
    const int f = idx - 59392;
    wsf[OFF_FDIAG + f] = (float)(_Float16)feat_W[f * 129];
  }
}

// ---- prep: i8 quant of W_ih columns (K=256, cc|m part), per-column scale ----
__global__ void prep_quant_wih(const float* __restrict__ Wih,
                               unsigned* __restrict__ wq, float* __restrict__ fscc) {
  const int col = blockIdx.x;                  // 2048 = 4*unit+gate
  const int unit = col >> 2, g = col & 3;
  const float* src = Wih + (size_t)(g * 512 + unit) * 256;
  const int t = threadIdx.x;                   // 64 threads (one wave), 4 k each
  const float4 v = ((const float4*)src)[t];
  float mx = fmaxf(fmaxf(fabsf(v.x), fabsf(v.y)), fmaxf(fabsf(v.z), fabsf(v.w)));
  mx = wave_max(mx);
  mx = __shfl(mx, 0, 64);
  const float s = (mx > 0.f) ? 127.f / mx : 0.f;
  const int q0 = __float2int_rn(v.x * s), q1 = __float2int_rn(v.y * s);
  const int q2 = __float2int_rn(v.z * s), q3 = __float2int_rn(v.w * s);
  wq[t * 2048 + col] =
      (q0 & 0xFF) | ((q1 & 0xFF) << 8) | ((q2 & 0xFF) << 16) | ((q3 & 0xFF) << 24);
  if (t == 0) fscc[col] = mx * DEQ_CC;
}

// ---- prep: i8 quant of W_hh columns (K=512, h part) ----
__global__ void prep_quant_whh(const float* __restrict__ Whh,
                               unsigned* __restrict__ wq, float* __restrict__ fschg) {
  const int col = blockIdx.x;
  const int unit = col >> 2, g = col & 3;
  const float* src = Whh + (size_t)(g * 512 + unit) * 512;
  const int t = threadIdx.x;                   // 128 threads, 4 k each
  const float4 v = ((const float4*)src)[t];
  float mx = fmaxf(fmaxf(fabsf(v.x), fabsf(v.y)), fmaxf(fabsf(v.z), fabsf(v.w)));
  mx = wave_max(mx);
  __shared__ float wm[2];
  if ((t & 63) == 0) wm[t >> 6] = mx;
  __syncthreads();
  const float maxv = fmaxf(wm[0], wm[1]);
  const float s = (maxv > 0.f) ? 127.f / maxv : 0.f;
  const int q0 = __float2int_rn(v.x * s), q1 = __float2int_rn(v.y * s);
  const int q2 = __float2int_rn(v.z * s), q3 = __float2int_rn(v.w * s);
  wq[t * 2048 + col] =
      (q0 & 0xFF) | ((q1 & 0xFF) << 8) | ((q2 & 0xFF) << 16) | ((q3 & 0xFF) << 24);
  if (t == 0) fschg[col] = maxv * DEQ_H;
}

// ---- prep: i8 quant of hist_W rows (K=512), ROW-major [f][k4] ----
__global__ void prep_quant_hist(const float* __restrict__ histW,
                                unsigned* __restrict__ histq, float* __restrict__ fsch) {
  const int f = blockIdx.x;                    // 128
  const float* src = histW + (size_t)f * 512;
  const int t = threadIdx.x;                   // 128 threads
  const float4 v = ((const float4*)src)[t];
  float mx = fmaxf(fmaxf(fabsf(v.x), fabsf(v.y)), fmaxf(fabsf(v.z), fabsf(v.w)));
  mx = wave_max(mx);
  __shared__ float wm[2];
  if ((t & 63) == 0) wm[t >> 6] = mx;
  __syncthreads();
  const float maxv = fmaxf(wm[0], wm[1]);
  const float s = (maxv > 0.f) ? 127.f / maxv : 0.f;
  const int q0 = __float2int_rn(v.x * s), q1 = __float2int_rn(v.y * s);
  const int q2 = __float2int_rn(v.z * s), q3 = __float2int_rn(v.w * s);
  histq[f * 128 + t] =
      (q0 & 0xFF) | ((q1 & 0xFF) << 8) | ((q2 & 0xFF) << 16) | ((q3 & 0xFF) << 24);
  if (t == 0) fsch[f] = maxv * DEQ_H;
}

// ---- main: 256 blocks x 1024 threads; 1 row/block.
//      Per step: stage -> S1 -> gamma_h (tid<512) -> S2 ->
//      [wave0: full F-chain serial, no barriers] || [waves1-15: gates-h stream]
//      -> S3 -> gates-cc (all) -> S4 -> LSTM (tid<512). 4 barriers/step. ----
__global__ void __launch_bounds__(NTHR) rits_batch(
    const float* __restrict__ x, const float* __restrict__ m, const float* __restrict__ d,
    const float* __restrict__ tx, const float* __restrict__ tmask,
    const float* __restrict__ td_h_b, const float* __restrict__ td_x_W,
    const float* __restrict__ td_x_b, const float* __restrict__ hist_b,
    const float* __restrict__ feat_b, const float* __restrict__ wc_b,
    const unsigned* __restrict__ wsu, const float* __restrict__ wsf,
    float* __restrict__ num, float* __restrict__ den, float* __restrict__ out)
{
  const int tid = threadIdx.x;
  const int row = blockIdx.x;
  const int lane = tid & 63, wv = tid >> 6;

  __shared__ __align__(16) unsigned actq_s[64];   // cc i8 words 0..31 | m i8 32..63
  __shared__ __align__(16) int      hq_s[128];    // decayed h i8 (scale 127)
  __shared__ __align__(16) unsigned d2_s[64];     // d f16 pairs
  __shared__ __align__(16) unsigned xc2_s[64];    // x_c f16 pairs
  __shared__ __align__(16) unsigned gxm2_s[128];  // gx pairs 0..63 | m pairs 64..127
  __shared__ float x_s[128], m_s[128], tx_s[128], ev_s[128];
  __shared__ float dxw_s[128], dxb_s[128];
  __shared__ int4  partHh_s[1024];                // gates-h partials [kh*512+unit]
  __shared__ int4  partHc_s[512];                 // gates-cc partials (kh=1)

  // persistent per-thread constants
  const int unit = tid & 511;
  const float4 bs    = *(const float4*)(wsf + OFF_BSUM + 4 * unit);
  const float4 fscc4 = *(const float4*)(wsf + OFF_FSCC + 4 * unit);
  const float4 fsch4 = *(const float4*)(wsf + OFF_FSCHG + 4 * unit);
  const float tdb = td_h_b[unit];

  // wave0 per-lane constants (features 2L, 2L+1)
  float2 fsf2{}, hb2{}, fb2{}, wb2{}, fd2{};
  if (tid < 64) {
    fsf2 = *(const float2*)(wsf + OFF_FSCH + 2 * tid);
    hb2  = *(const float2*)(hist_b + 2 * tid);
    fb2  = *(const float2*)(feat_b + 2 * tid);
    wb2  = *(const float2*)(wc_b + 2 * tid);
    fd2  = *(const float2*)(wsf + OFF_FDIAG + 2 * tid);
  }
  if (tid < 128) { dxw_s[tid] = td_x_W[tid * 129]; dxb_s[tid] = td_x_b[tid]; }

  float h0 = 0.f, c0 = 0.f;                    // recurrent state (tid<512)
  __syncthreads();

  for (int t = 0; t < T; ++t) {
    const int base = (row * T + t) * F;

    // ---- STAGE: this step's input row ----
    if (tid < 512) {
      const int a = tid >> 7, f = tid & 127;
      const float v = (a == 0 ? x[base + f] : a == 1 ? m[base + f]
                       : a == 2 ? tx[base + f] : tmask[base + f]);
      if      (a == 0) x_s[f]  = v;
      else if (a == 1) m_s[f]  = v;
      else if (a == 2) tx_s[f] = v;
      else             ev_s[f] = v;
    } else if (tid < 576) {
      const int j = tid - 512;
      d2_s[j] = pack2(d[base + 2 * j], d[base + 2 * j + 1]);
    } else if (tid < 640) {
      const int j = tid - 576;
      gxm2_s[64 + j] = pack2(m[base + 2 * j], m[base + 2 * j + 1]);
    } else if (tid < 704) {
      const int j = tid - 640;
      const float dv0 = d[base + 2 * j], dv1 = d[base + 2 * j + 1];
      const float gx0 = __expf(-fmaxf(fmaf(dv0, dxw_s[2 * j], dxb_s[2 * j]), 0.f));
      const float gx1 = __expf(-fmaxf(fmaf(dv1, dxw_s[2 * j + 1], dxb_s[2 * j + 1]), 0.f));
      gxm2_s[j] = pack2(gx0, gx1);
    } else if (tid < 736) {
      const int w = tid - 704;
      const int b4 = base + 4 * w;
      const int q0 = __float2int_rn(m[b4] * ACT_S);
      const int q1 = __float2int_rn(m[b4 + 1] * ACT_S);
      const int q2 = __float2int_rn(m[b4 + 2] * ACT_S);
      const int q3 = __float2int_rn(m[b4 + 3] * ACT_S);
      actq_s[32 + w] =
          (q0 & 0xFF) | ((q1 & 0xFF) << 8) | ((q2 & 0xFF) << 16) | ((q3 & 0xFF) << 24);
    }
    __syncthreads();   // S1

    // ---- GAMMA_H (tid<512, row-major TD2, uint4 loads), publish hq ----
    if (tid < 512) {
      float g0 = tdb;
      const uint4* tw = (const uint4*)(wsu + OFF_TD2 + (size_t)tid * 64);
      const uint4* dw = (const uint4*)d2_s;
#pragma unroll 8
      for (int q = 0; q < 16; ++q) {
        const uint4 w = tw[q], dd = dw[q];
        g0 = fdot2(as_h2(w.x), as_h2(dd.x), g0);
        g0 = fdot2(as_h2(w.y), as_h2(dd.y), g0);
        g0 = fdot2(as_h2(w.z), as_h2(dd.z), g0);
        g0 = fdot2(as_h2(w.w), as_h2(dd.w), g0);
      }
      h0 *= __expf(-fmaxf(g0, 0.f));
      int q = __float2int_rn(h0 * 127.f);
      const int a1 = __shfl_down(q, 1, 64), a2 = __shfl_down(q, 2, 64), a3 = __shfl_down(q, 3, 64);
      if ((tid & 3) == 0)
        hq_s[tid >> 2] =
            (q & 0xFF) | ((a1 & 0xFF) << 8) | ((a2 & 0xFF) << 16) | ((a3 & 0xFF) << 24);
    }
    __syncthreads();   // S2

    if (wv == 0) {
      // ======== wave 0: serial F-chain (no block barriers needed) ========
      const int L = tid;                       // features 2L, 2L+1
      // E: x_hist (full K=512 i8 dot per feature)
      int is0 = 0, is1 = 0;
      {
        const uint4* hq4 = (const uint4*)hq_s;
        const uint4* hw0 = (const uint4*)(wsu + OFF_HISTQ + (size_t)(2 * L) * 128);
        const uint4* hw1 = (const uint4*)(wsu + OFF_HISTQ + (size_t)(2 * L + 1) * 128);
#pragma unroll 8
        for (int k = 0; k < 32; ++k) {
          const uint4 a = hq4[k];
          const uint4 w0 = hw0[k], w1 = hw1[k];
          is0 = sdot4((int)w0.x, (int)a.x, is0); is1 = sdot4((int)w1.x, (int)a.x, is1);
          is0 = sdot4((int)w0.y, (int)a.y, is0); is1 = sdot4((int)w1.y, (int)a.y, is1);
          is0 = sdot4((int)w0.z, (int)a.z, is0); is1 = sdot4((int)w1.z, (int)a.z, is1);
          is0 = sdot4((int)w0.w, (int)a.w, is0); is1 = sdot4((int)w1.w, (int)a.w, is1);
        }
      }
      const float xh0 = fmaf((float)is0, fsf2.x, hb2.x);
      const float xh1 = fmaf((float)is1, fsf2.y, hb2.y);
      const float mv0 = m_s[2 * L], mv1 = m_s[2 * L + 1];
      const float xv0 = x_s[2 * L], xv1 = x_s[2 * L + 1];
      const float xc0 = mv0 * xv0 + (1.f - mv0) * xh0;
      const float xc1 = mv1 * xv1 + (1.f - mv1) * xh1;
      xc2_s[L] = pack2(xc0, xc1);              // same-wave LDS: ordered by lgkmcnt
      // G: feat (K=128) + alpha (K=256) f16 dots
      float z0 = fb2.x, z1 = fb2.y, aa0 = wb2.x, aa1 = wb2.y;
      {
        const uint4* fw0 = (const uint4*)(wsu + OFF_FEAT2 + (size_t)(2 * L) * 64);
        const uint4* fw1 = (const uint4*)(wsu + OFF_FEAT2 + (size_t)(2 * L + 1) * 64);
        const uint4* xcw = (const uint4*)xc2_s;
#pragma unroll 8
        for (int k = 0; k < 16; ++k) {
          const uint4 w0 = fw0[k], w1 = fw1[k], xv = xcw[k];
          z0 = fdot2(as_h2(w0.x), as_h2(xv.x), z0); z1 = fdot2(as_h2(w1.x), as_h2(xv.x), z1);
          z0 = fdot2(as_h2(w0.y), as_h2(xv.y), z0); z1 = fdot2(as_h2(w1.y), as_h2(xv.y), z1);
          z0 = fdot2(as_h2(w0.z), as_h2(xv.z), z0); z1 = fdot2(as_h2(w1.z), as_h2(xv.z), z1);
          z0 = fdot2(as_h2(w0.w), as_h2(xv.w), z0); z1 = fdot2(as_h2(w1.w), as_h2(xv.w), z1);
        }
        const uint4* ww0 = (const uint4*)(wsu + OFF_WC2 + (size_t)(2 * L) * 128);
        const uint4* ww1 = (const uint4*)(wsu + OFF_WC2 + (size_t)(2 * L + 1) * 128);
        const uint4* gw = (const uint4*)gxm2_s;
#pragma unroll 8
        for (int k = 0; k < 32; ++k) {
          const uint4 w0 = ww0[k], w1 = ww1[k], gv = gw[k];
          aa0 = fdot2(as_h2(w0.x), as_h2(gv.x), aa0); aa1 = fdot2(as_h2(w1.x), as_h2(gv.x), aa1);
          aa0 = fdot2(as_h2(w0.y), as_h2(gv.y), aa0); aa1 = fdot2(as_h2(w1.y), as_h2(gv.y), aa1);
          aa0 = fdot2(as_h2(w0.z), as_h2(gv.z), aa0); aa1 = fdot2(as_h2(w1.z), as_h2(gv.z), aa1);
          aa0 = fdot2(as_h2(w0.w), as_h2(gv.w), aa0); aa1 = fdot2(as_h2(w1.w), as_h2(gv.w), aa1);
        }
      }
      z0 -= xc0 * fd2.x; z1 -= xc1 * fd2.y;    // remove diagonal
      const float al0 = fast_sig(aa0), al1 = fast_sig(aa1);
      const float ch0 = al0 * z0 + (1.f - al0) * xh0;
      const float ch1 = al1 * z1 + (1.f - al1) * xh1;
      const float cc0 = mv0 * xv0 + (1.f - mv0) * ch0;
      const float cc1 = mv1 * xv1 + (1.f - mv1) * ch1;
      ((float2*)(out + base))[L] = float2{cc0, cc1};
      // loss partials
      const float tg0 = tx_s[2 * L], tg1 = tx_s[2 * L + 1];
      const float ev0 = ev_s[2 * L], ev1 = ev_s[2 * L + 1];
      const float e10 = xh0 - tg0, e20 = z0 - tg0, e30 = ch0 - tg0;
      const float e11 = xh1 - tg1, e21 = z1 - tg1, e31 = ch1 - tg1;
      float s1 = ev0 * (e10 * e10 + e20 * e20 + e30 * e30)
               + ev1 * (e11 * e11 + e21 * e21 + e31 * e31);
      float s2 = ev0 + ev1;
      s1 = wave_sum(s1); s2 = wave_sum(s2);
      if (L == 0) { atomicAdd(&num[t], s1); atomicAdd(&den[t], s2); }
      // pack cc -> i8 (4 features per word, pairs of lanes)
      const int q0 = __float2int_rn(fminf(fmaxf(cc0, -8.f), 8.f) * ACT_S);
      const int q1 = __float2int_rn(fminf(fmaxf(cc1, -8.f), 8.f) * ACT_S);
      const unsigned u16 = (unsigned)(q0 & 0xFF) | ((unsigned)(q1 & 0xFF) << 8);
      const unsigned o16 = __shfl_down(u16, 1, 64);
      if (!(L & 1)) actq_s[L >> 1] = u16 | (o16 << 16);
    } else {
      // ======== waves 1-15: gates-h stream (1 MB W_hh, K split 2) ========
      const int t1 = tid - 64;
      for (int tt = t1; tt < 1024; tt += 960) {
        const int u2 = tt & 511, khh = tt >> 9;
        const unsigned* wp = wsu + OFF_WQH + ((size_t)khh * 64) * 2048 + 4 * u2;
        const int* hqp = hq_s + khh * 64;
        int hi = 0, hf = 0, hg = 0, ho = 0;
#pragma unroll 16
        for (int k = 0; k < 64; ++k) {
          const uint4 w = *(const uint4*)(wp + (size_t)k * 2048);
          const int a0 = hqp[k];
          hi = sdot4((int)w.x, a0, hi); hf = sdot4((int)w.y, a0, hf);
          hg = sdot4((int)w.z, a0, hg); ho = sdot4((int)w.w, a0, ho);
        }
        partHh_s[tt] = int4{hi, hf, hg, ho};
      }
    }
    __syncthreads();   // S3

    // ---- gates cc|m part (all 16 waves, K split 2) + LSTM ----
    {
      const int kh = tid >> 9;
      int ci = 0, cf = 0, cg = 0, co = 0;
      const unsigned* wq = wsu + OFF_WQCC + 4 * unit;
#pragma unroll 16
      for (int k = 0; k < 32; ++k) {
        const int k4 = kh * 32 + k;
        const uint4 w = *(const uint4*)(wq + ((size_t)k4 << 11));
        const int a0 = (int)actq_s[k4];
        ci = sdot4((int)w.x, a0, ci); cf = sdot4((int)w.y, a0, cf);
        cg = sdot4((int)w.z, a0, cg); co = sdot4((int)w.w, a0, co);
      }
      if (tid >= 512) partHc_s[unit] = int4{ci, cf, cg, co};
      __syncthreads();   // S4
      if (tid < 512) {
        const int4 pc = partHc_s[unit];
        const int4 p0 = partHh_s[unit], p1 = partHh_s[unit + 512];
        const float ai = bs.x + fscc4.x * (float)(ci + pc.x) + fsch4.x * (float)(p0.x + p1.x);
        const float af = bs.y + fscc4.y * (float)(cf + pc.y) + fsch4.y * (float)(p0.y + p1.y);
        const float ag = bs.z + fscc4.z * (float)(cg + pc.z) + fsch4.z * (float)(p0.z + p1.z);
        const float ao = bs.w + fscc4.w * (float)(co + pc.w) + fsch4.w * (float)(p0.w + p1.w);
        const float ig = fast_sig(ai), fg = fast_sig(af);
        const float gg = fast_tanh(ag), og = fast_sig(ao);
        c0 = fg * c0 + ig * gg;
        h0 = og * fast_tanh(c0);
      }
    }
    // no trailing barrier: next stage's LDS writes are all protected by S1,
    // and every reader of this step's buffers finished before S4.
  }
}

__global__ void finalize(const float* __restrict__ num, const float* __restrict__ den,
                         float* __restrict__ out) {
  __shared__ float red[2];
  const int t = threadIdx.x;     // 128 threads
  float v = num[t] / (den[t] + 1e-8f);
  v = wave_sum(v);
  if ((t & 63) == 0) red[t >> 6] = v;
  __syncthreads();
  if (t == 0) out[(size_t)B * T * F] = (red[0] + red[1]) / (float)T;
}

extern "C" void kernel_launch(void* const* d_in, const int* in_sizes, int n_in,
                              void* d_out, int out_size, void* d_ws, size_t ws_size,
                              hipStream_t stream) {
  const float* x      = (const float*)d_in[0];
  const float* m      = (const float*)d_in[1];
  const float* d      = (const float*)d_in[2];
  const float* tx     = (const float*)d_in[3];
  const float* tmask  = (const float*)d_in[4];
  const float* td_h_W = (const float*)d_in[5];
  const float* td_h_b = (const float*)d_in[6];
  const float* td_x_W = (const float*)d_in[7];
  const float* td_x_b = (const float*)d_in[8];
  const float* hist_W = (const float*)d_in[9];
  const float* hist_b = (const float*)d_in[10];
  const float* feat_W = (const float*)d_in[11];
  const float* feat_b = (const float*)d_in[12];
  const float* wc_W   = (const float*)d_in[13];
  const float* wc_b   = (const float*)d_in[14];
  const float* W_ih   = (const float*)d_in[15];
  const float* W_hh   = (const float*)d_in[16];
  const float* b_ih   = (const float*)d_in[17];
  const float* b_hh   = (const float*)d_in[18];

  float*    wsf = (float*)d_ws;
  unsigned* wsu = (unsigned*)d_ws;
  float*    out = (float*)d_out;

  if (ws_size < WS_WORDS * 4) return;   // OOB tripwire

  hipMemsetAsync(d_ws, 0, 256 * sizeof(float), stream);   // num/den
  prep_f16<<<dim3((59520 + 255) / 256), dim3(256), 0, stream>>>(
      td_h_W, feat_W, wc_W, b_ih, b_hh, wsu, wsf);
  prep_quant_wih<<<dim3(2048), dim3(64), 0, stream>>>(
      W_ih, wsu + OFF_WQCC, wsf + OFF_FSCC);
  prep_quant_whh<<<dim3(2048), dim3(128), 0, stream>>>(
      W_hh, wsu + OFF_WQH, wsf + OFF_FSCHG);
  prep_quant_hist<<<dim3(128), dim3(128), 0, stream>>>(
      hist_W, wsu + OFF_HISTQ, wsf + OFF_FSCH);
  rits_batch<<<dim3(NBLK), dim3(NTHR), 0, stream>>>(
      x, m, d, tx, tmask, td_h_b, td_x_W, td_x_b, hist_b, feat_b, wc_b,
      wsu, wsf, wsf + OFF_NUM, wsf + OFF_DEN, out);
  finalize<<<dim3(1), dim3(128), 0, stream>>>(wsf + OFF_NUM, wsf + OFF_DEN, out);
}

// Round 3
// 3036.842 us; speedup vs baseline: 1.7567x; 1.3964x over previous
//
#include <hip/hip_runtime.h>

#define DEVINL __device__ __forceinline__

namespace {
constexpr int B = 256, T = 128, F = 128, H = 512;
constexpr int NBLK = 256;        // 1 batch row per block
constexpr int NTHR = 1024;       // 16 waves: 2 F-waves + 14 stream waves

// workspace layout in 4-byte words (same as round 2)
constexpr size_t OFF_NUM    = 0;                         // [128] loss numerators
constexpr size_t OFF_DEN    = 128;                       // [128] denominators
constexpr size_t OFF_WQCC   = 256;                       // gates cc|m i8x4 [64 k4][2048 col]
constexpr size_t OFF_WQH    = OFF_WQCC + 64 * 2048;      // gates h    i8x4 [128 k4][2048 col]
constexpr size_t OFF_FSCC   = OFF_WQH + 128 * 2048;      // [2048] colmax/(127*15.875)
constexpr size_t OFF_FSCHG  = OFF_FSCC + 2048;           // [2048] colmax/16129
constexpr size_t OFF_HISTQ  = OFF_FSCHG + 2048;          // hist i8x4 [128 f][128 k4] ROW-major
constexpr size_t OFF_FSCH   = OFF_HISTQ + 128 * 128;     // [128] colmax/16129
constexpr size_t OFF_TD2    = OFF_FSCH + 128;            // td_h f16x2 [512 u][64 k2] ROW-major
constexpr size_t OFF_FEAT2  = OFF_TD2 + 64 * 512;        // feat f16x2 [128 f][64 k2] ROW-major
constexpr size_t OFF_WC2    = OFF_FEAT2 + 64 * 128;      // wc   f16x2 [128 f][128 k2] ROW-major
constexpr size_t OFF_BSUM   = OFF_WC2 + 128 * 128;       // [2048] b_ih+b_hh gate-interleaved
constexpr size_t OFF_FDIAG  = OFF_BSUM + 2048;           // [128] f16-rounded feat diag
constexpr size_t WS_WORDS   = OFF_FDIAG + 128;           // ~1.81 MB

constexpr float ACT_S  = 15.875f;                // cc|m activation scale (clamp +-8)
constexpr float DEQ_CC = 1.f / (127.f * 15.875f);
constexpr float DEQ_H  = 1.f / (127.f * 127.f);

constexpr int FH = 0, FX = 1, FD = 2, FA = 3, FS = 4, FL = 5;
}

typedef _Float16 h2_t __attribute__((ext_vector_type(2)));

DEVINL h2_t as_h2(unsigned u) { union { unsigned u; h2_t h; } c; c.u = u; return c.h; }
DEVINL unsigned pack2(float a, float b) {
  union { h2_t h; unsigned u; } c;
  c.h = h2_t{(_Float16)a, (_Float16)b};
  return c.u;
}
DEVINL unsigned pack4i(int a, int b, int c, int d) {
  return (a & 0xFF) | ((b & 0xFF) << 8) | ((c & 0xFF) << 16) | ((d & 0xFF) << 24);
}

#if defined(__has_builtin)
#if __has_builtin(__builtin_amdgcn_fdot2)
#define HAVE_FDOT2 1
#endif
#if __has_builtin(__builtin_amdgcn_sdot4)
#define HAVE_SDOT4 1
#endif
#endif
#ifdef HAVE_FDOT2
DEVINL float fdot2(h2_t a, h2_t b, float c) { return __builtin_amdgcn_fdot2(a, b, c, false); }
#else
DEVINL float fdot2(h2_t a, h2_t b, float c) {
  return fmaf((float)a.x, (float)b.x, fmaf((float)a.y, (float)b.y, c));
}
#endif
#ifdef HAVE_SDOT4
DEVINL int sdot4(int a, int b, int c) { return __builtin_amdgcn_sdot4(a, b, c, false); }
#else
DEVINL int sdot4(int a, int b, int c) {
  return c + ((a << 24) >> 24) * ((b << 24) >> 24)
           + ((a << 16) >> 24) * ((b << 16) >> 24)
           + ((a << 8) >> 24) * ((b << 8) >> 24)
           + (a >> 24) * (b >> 24);
}
#endif

DEVINL float fast_sig(float x)  { return 1.f / (1.f + __expf(-x)); }
DEVINL float fast_tanh(float x) { return 1.f - 2.f / (1.f + __expf(2.f * x)); }

DEVINL float wave_sum(float v) {
#pragma unroll
  for (int s = 32; s; s >>= 1) v += __shfl_down(v, s, 64);
  return v;
}
DEVINL float wave_max(float v) {
#pragma unroll
  for (int s = 32; s; s >>= 1) v = fmaxf(v, __shfl_down(v, s, 64));
  return v;
}

// LDS flag sync: release-add by wave lane0, acquire-spin by all lanes.
DEVINL void flag_add(unsigned* p) {
  __hip_atomic_fetch_add(p, 1u, __ATOMIC_RELEASE, __HIP_MEMORY_SCOPE_WORKGROUP);
}
DEVINL void spin_ge(const unsigned* p, unsigned tgt) {
  int guard = 0;
  while (__hip_atomic_load(p, __ATOMIC_ACQUIRE, __HIP_MEMORY_SCOPE_WORKGROUP) < tgt) {
    __builtin_amdgcn_s_sleep(1);
    if (++guard > (1 << 24)) break;   // hang tripwire (wrong answer beats a hang)
  }
}

// ---- prep: f16 tables + biases (all row-major per consumer thread) ----
__global__ void prep_f16(const float* __restrict__ td_h_W, const float* __restrict__ feat_W,
                         const float* __restrict__ wc_W, const float* __restrict__ b_ih,
                         const float* __restrict__ b_hh,
                         unsigned* __restrict__ wsu, float* __restrict__ wsf) {
  int idx = blockIdx.x * blockDim.x + threadIdx.x;
  if (idx < 32768) {                           // TD2 [512 u][64 k2]
    const int u = idx >> 6, k2 = idx & 63;
    wsu[OFF_TD2 + idx] = pack2(td_h_W[u * 128 + 2 * k2], td_h_W[u * 128 + 2 * k2 + 1]);
  } else if (idx < 40960) {                    // FEAT2 [128 f][64 k2]
    const int i = idx - 32768, f = i >> 6, k2 = i & 63;
    wsu[OFF_FEAT2 + i] = pack2(feat_W[f * 128 + 2 * k2], feat_W[f * 128 + 2 * k2 + 1]);
  } else if (idx < 57344) {                    // WC2 [128 f][128 k2]
    const int i = idx - 40960, f = i >> 7, k2 = i & 127;
    wsu[OFF_WC2 + i] = pack2(wc_W[f * 256 + 2 * k2], wc_W[f * 256 + 2 * k2 + 1]);
  } else if (idx < 59392) {                    // BSUM [2048]
    const int i = idx - 57344, unit = i >> 2, g = i & 3;
    wsf[OFF_BSUM + i] = b_ih[g * 512 + unit] + b_hh[g * 512 + unit];
  } else if (idx < 59520) {                    // FDIAG [128]
    const int f = idx - 59392;
    wsf[OFF_FDIAG + f] = (float)(_Float16)feat_W[f * 129];
  }
}

// ---- prep: i8 quant of W_ih columns (K=256, cc|m), per-column scale ----
__global__ void prep_quant_wih(const float* __restrict__ Wih,
                               unsigned* __restrict__ wq, float* __restrict__ fscc) {
  const int col = blockIdx.x;                  // 2048 = 4*unit+gate
  const int unit = col >> 2, g = col & 3;
  const float* src = Wih + (size_t)(g * 512 + unit) * 256;
  const int t = threadIdx.x;                   // 64 threads
  const float4 v = ((const float4*)src)[t];
  float mx = fmaxf(fmaxf(fabsf(v.x), fabsf(v.y)), fmaxf(fabsf(v.z), fabsf(v.w)));
  mx = wave_max(mx);
  mx = __shfl(mx, 0, 64);
  const float s = (mx > 0.f) ? 127.f / mx : 0.f;
  wq[t * 2048 + col] = pack4i(__float2int_rn(v.x * s), __float2int_rn(v.y * s),
                              __float2int_rn(v.z * s), __float2int_rn(v.w * s));
  if (t == 0) fscc[col] = mx * DEQ_CC;
}

// ---- prep: i8 quant of W_hh columns (K=512, h part) ----
__global__ void prep_quant_whh(const float* __restrict__ Whh,
                               unsigned* __restrict__ wq, float* __restrict__ fschg) {
  const int col = blockIdx.x;
  const int unit = col >> 2, g = col & 3;
  const float* src = Whh + (size_t)(g * 512 + unit) * 512;
  const int t = threadIdx.x;                   // 128 threads
  const float4 v = ((const float4*)src)[t];
  float mx = fmaxf(fmaxf(fabsf(v.x), fabsf(v.y)), fmaxf(fabsf(v.z), fabsf(v.w)));
  mx = wave_max(mx);
  __shared__ float wm[2];
  if ((t & 63) == 0) wm[t >> 6] = mx;
  __syncthreads();
  const float maxv = fmaxf(wm[0], wm[1]);
  const float s = (maxv > 0.f) ? 127.f / maxv : 0.f;
  wq[t * 2048 + col] = pack4i(__float2int_rn(v.x * s), __float2int_rn(v.y * s),
                              __float2int_rn(v.z * s), __float2int_rn(v.w * s));
  if (t == 0) fschg[col] = maxv * DEQ_H;
}

// ---- prep: i8 quant of hist_W rows (K=512), ROW-major [f][k4] ----
__global__ void prep_quant_hist(const float* __restrict__ histW,
                                unsigned* __restrict__ histq, float* __restrict__ fsch) {
  const int f = blockIdx.x;                    // 128
  const float* src = histW + (size_t)f * 512;
  const int t = threadIdx.x;                   // 128 threads
  const float4 v = ((const float4*)src)[t];
  float mx = fmaxf(fmaxf(fabsf(v.x), fabsf(v.y)), fmaxf(fabsf(v.z), fabsf(v.w)));
  mx = wave_max(mx);
  __shared__ float wm[2];
  if ((t & 63) == 0) wm[t >> 6] = mx;
  __syncthreads();
  const float maxv = fmaxf(wm[0], wm[1]);
  const float s = (maxv > 0.f) ? 127.f / maxv : 0.f;
  histq[f * 128 + t] = pack4i(__float2int_rn(v.x * s), __float2int_rn(v.y * s),
                              __float2int_rn(v.z * s), __float2int_rn(v.w * s));
  if (t == 0) fsch[f] = maxv * DEQ_H;
}

// ---- main: wave-specialized. F-group (waves 0-1): full F-chain, 1 feature/thread,
//      full-K dots (no reductions). Stream group (waves 2-15): 1.5 MB gate stream as
//      3072 items; LSTM on 8 stream waves. All sync via monotone LDS flags. ----
__global__ void __launch_bounds__(NTHR) rits_batch(
    const float* __restrict__ x, const float* __restrict__ m, const float* __restrict__ d,
    const float* __restrict__ tx, const float* __restrict__ tmask,
    const float* __restrict__ td_h_b, const float* __restrict__ td_x_W,
    const float* __restrict__ td_x_b, const float* __restrict__ hist_b,
    const float* __restrict__ feat_b, const float* __restrict__ wc_b,
    const unsigned* __restrict__ wsu, const float* __restrict__ wsf,
    float* __restrict__ num, float* __restrict__ den, float* __restrict__ out)
{
  const int tid = threadIdx.x;
  const int row = blockIdx.x;

  __shared__ __align__(16) unsigned hq_s[128];      // decayed h i8 (scale 127)
  __shared__ __align__(16) unsigned actq_s[2][64];  // cc i8 0..31 | m i8 32..63 (parity)
  __shared__ __align__(16) unsigned gxm2_s[2][128]; // gx pairs 0..63 | m pairs 64..127
  __shared__ __align__(16) unsigned d2_s[64];       // d f16 pairs (F-internal)
  __shared__ __align__(16) unsigned xc2_s[64];      // x_c f16 pairs
  __shared__ __align__(16) float gexp_s[512];       // prefetched exp(-relu(td.d))
  __shared__ __align__(16) float h_s[512];          // recurrent h
  __shared__ __align__(16) int4 partH_s[4][512];    // gates-h partials by k-quarter
  __shared__ __align__(16) int4 partC_s[2][512];    // gates-cc partials (0=cc,1=m)
  __shared__ unsigned flg[6];

  if (tid < 512) { h_s[tid] = 0.f; gexp_s[tid] = 0.f; }
  if (tid < 6) flg[tid] = 0u;
  __syncthreads();

  if (tid < 128) {
    // ================= F-group: waves 0-1 =================
    const int f = tid;
    const float hb = hist_b[f], fb = feat_b[f], wb = wc_b[f];
    const float fd = wsf[OFF_FDIAG + f], fsf = wsf[OFF_FSCH + f];
    const float dxw = td_x_W[f * 129], dxb = td_x_b[f];
    const float4 tdb4 = *(const float4*)(td_h_b + 4 * tid);

    // pre-stage t=0 inputs (regs) + gxm2[0] + actq[0] m-part
    float x_r, m_r, d_r, tx_r, ev_r;
    {
      const size_t b0 = (size_t)row * T * F + f;
      x_r = x[b0]; m_r = m[b0]; d_r = d[b0]; tx_r = tx[b0]; ev_r = tmask[b0];
      const float gx = __expf(-fmaxf(fmaf(d_r, dxw, dxb), 0.f));
      const float gxs = __shfl_down(gx, 1, 64);
      const float ms  = __shfl_down(m_r, 1, 64);
      if (!(f & 1)) {
        gxm2_s[0][f >> 1] = pack2(gx, gxs);
        gxm2_s[0][64 + (f >> 1)] = pack2(m_r, ms);
      }
      const int qm = __float2int_rn(m_r * ACT_S);
      const int q1 = __shfl_down(qm, 1, 64), q2 = __shfl_down(qm, 2, 64), q3 = __shfl_down(qm, 3, 64);
      if (!(f & 3)) actq_s[0][32 + (f >> 2)] = pack4i(qm, q1, q2, q3);
    }

    for (int t = 0; t < T; ++t) {
      const size_t base = ((size_t)row * T + t) * F;
      const int par = t & 1;

      // ph1: wait LSTM(t-1); decay h via prefetched gexp; quantize; publish hq
      if (t) { spin_ge(&flg[FL], 8u * (unsigned)t); __threadfence_block(); }
      {
        const float4 h4 = *(const float4*)(h_s + 4 * tid);
        const float4 g4 = *(const float4*)(gexp_s + 4 * tid);
        hq_s[tid] = pack4i(__float2int_rn(h4.x * g4.x * 127.f),
                           __float2int_rn(h4.y * g4.y * 127.f),
                           __float2int_rn(h4.z * g4.z * 127.f),
                           __float2int_rn(h4.w * g4.w * 127.f));
      }
      __threadfence_block();
      if (!(tid & 63)) flag_add(&flg[FH]);
      spin_ge(&flg[FH], 2u * (unsigned)(t + 1)); __threadfence_block();

      // ph2: x_hist full-K i8 dot (own hist row), x_c, publish xc2
      int is = 0;
      {
        const uint4* hw = (const uint4*)(wsu + OFF_HISTQ + (size_t)f * 128);
        const uint4* hq4 = (const uint4*)hq_s;
#pragma unroll 8
        for (int k = 0; k < 32; ++k) {
          const uint4 w = hw[k], a = hq4[k];
          is = sdot4((int)w.x, (int)a.x, is);
          is = sdot4((int)w.y, (int)a.y, is);
          is = sdot4((int)w.z, (int)a.z, is);
          is = sdot4((int)w.w, (int)a.w, is);
        }
      }
      const float xh = fmaf((float)is, fsf, hb);
      const float xc = m_r * x_r + (1.f - m_r) * xh;
      {
        const float xcs = __shfl_down(xc, 1, 64);
        if (!(f & 1)) xc2_s[f >> 1] = pack2(xc, xcs);
      }
      __threadfence_block();
      if (!(tid & 63)) flag_add(&flg[FX]);
      spin_ge(&flg[FX], 2u * (unsigned)(t + 1)); __threadfence_block();

      // ph3: feat (K=128) + alpha (K=256) full-K f16 dots; outputs; loss
      float z = fb, aa = wb;
      {
        const uint4* fw = (const uint4*)(wsu + OFF_FEAT2 + (size_t)f * 64);
        const uint4* xw = (const uint4*)xc2_s;
#pragma unroll 8
        for (int k = 0; k < 16; ++k) {
          const uint4 w = fw[k], v = xw[k];
          z = fdot2(as_h2(w.x), as_h2(v.x), z);
          z = fdot2(as_h2(w.y), as_h2(v.y), z);
          z = fdot2(as_h2(w.z), as_h2(v.z), z);
          z = fdot2(as_h2(w.w), as_h2(v.w), z);
        }
        const uint4* ww = (const uint4*)(wsu + OFF_WC2 + (size_t)f * 128);
        const uint4* gw = (const uint4*)gxm2_s[par];
#pragma unroll 8
        for (int k = 0; k < 32; ++k) {
          const uint4 w = ww[k], g = gw[k];
          aa = fdot2(as_h2(w.x), as_h2(g.x), aa);
          aa = fdot2(as_h2(w.y), as_h2(g.y), aa);
          aa = fdot2(as_h2(w.z), as_h2(g.z), aa);
          aa = fdot2(as_h2(w.w), as_h2(g.w), aa);
        }
      }
      z -= xc * fd;                            // remove diagonal
      const float al = fast_sig(aa);
      const float ch = al * z + (1.f - al) * xh;
      const float cc = m_r * x_r + (1.f - m_r) * ch;
      out[base + f] = cc;
      const float e1 = xh - tx_r, e2 = z - tx_r, e3 = ch - tx_r;
      const float s1 = wave_sum(ev_r * (e1 * e1 + e2 * e2 + e3 * e3));
      const float s2 = wave_sum(ev_r);
      if (!(tid & 63)) { atomicAdd(&num[t], s1); atomicAdd(&den[t], s2); }

      // ph4: quantize cc -> actq cc-part; signal
      {
        const int qc = __float2int_rn(fminf(fmaxf(cc, -8.f), 8.f) * ACT_S);
        const int c1 = __shfl_down(qc, 1, 64), c2 = __shfl_down(qc, 2, 64), c3 = __shfl_down(qc, 3, 64);
        if (!(f & 3)) actq_s[par][f >> 2] = pack4i(qc, c1, c2, c3);
      }
      __threadfence_block();
      if (!(tid & 63)) flag_add(&flg[FA]);

      // ph5+ph6: stage t+1 inputs + prefetch gamma-dot (overlaps gate stream)
      if (t + 1 < T) {
        const size_t b2 = base + F + f;
        x_r = x[b2]; m_r = m[b2]; d_r = d[b2]; tx_r = tx[b2]; ev_r = tmask[b2];
        const float gx = __expf(-fmaxf(fmaf(d_r, dxw, dxb), 0.f));
        const float gxs = __shfl_down(gx, 1, 64);
        const float ms  = __shfl_down(m_r, 1, 64);
        const float dsh = __shfl_down(d_r, 1, 64);
        if (!(f & 1)) {
          gxm2_s[par ^ 1][f >> 1] = pack2(gx, gxs);
          gxm2_s[par ^ 1][64 + (f >> 1)] = pack2(m_r, ms);
          d2_s[f >> 1] = pack2(d_r, dsh);
        }
        const int qm = __float2int_rn(m_r * ACT_S);
        const int q1 = __shfl_down(qm, 1, 64), q2 = __shfl_down(qm, 2, 64), q3 = __shfl_down(qm, 3, 64);
        if (!(f & 3)) actq_s[par ^ 1][32 + (f >> 2)] = pack4i(qm, q1, q2, q3);
        __threadfence_block();
        if (!(tid & 63)) flag_add(&flg[FD]);
        spin_ge(&flg[FD], 2u * (unsigned)(t + 1)); __threadfence_block();
        // gamma-dot for t+1: 4 units/thread, TD2 row-major
        float g0 = tdb4.x, g1 = tdb4.y, g2 = tdb4.z, g3 = tdb4.w;
        const uint4* t0 = (const uint4*)(wsu + OFF_TD2 + ((size_t)tid * 4) * 64);
        const uint4* dw = (const uint4*)d2_s;
#pragma unroll 4
        for (int k = 0; k < 16; ++k) {
          const uint4 dd = dw[k];
          uint4 w = t0[k];
          g0 = fdot2(as_h2(w.x), as_h2(dd.x), g0); g0 = fdot2(as_h2(w.y), as_h2(dd.y), g0);
          g0 = fdot2(as_h2(w.z), as_h2(dd.z), g0); g0 = fdot2(as_h2(w.w), as_h2(dd.w), g0);
          w = t0[k + 16];
          g1 = fdot2(as_h2(w.x), as_h2(dd.x), g1); g1 = fdot2(as_h2(w.y), as_h2(dd.y), g1);
          g1 = fdot2(as_h2(w.z), as_h2(dd.z), g1); g1 = fdot2(as_h2(w.w), as_h2(dd.w), g1);
          w = t0[k + 32];
          g2 = fdot2(as_h2(w.x), as_h2(dd.x), g2); g2 = fdot2(as_h2(w.y), as_h2(dd.y), g2);
          g2 = fdot2(as_h2(w.z), as_h2(dd.z), g2); g2 = fdot2(as_h2(w.w), as_h2(dd.w), g2);
          w = t0[k + 48];
          g3 = fdot2(as_h2(w.x), as_h2(dd.x), g3); g3 = fdot2(as_h2(w.y), as_h2(dd.y), g3);
          g3 = fdot2(as_h2(w.z), as_h2(dd.z), g3); g3 = fdot2(as_h2(w.w), as_h2(dd.w), g3);
        }
        *(float4*)(gexp_s + 4 * tid) = float4{
            __expf(-fmaxf(g0, 0.f)), __expf(-fmaxf(g1, 0.f)),
            __expf(-fmaxf(g2, 0.f)), __expf(-fmaxf(g3, 0.f))};
        // consumed by ph1(t+1): same threads, program order; no flag needed
      }
    }
  } else {
    // ================= stream group: waves 2-15 (896 threads) =================
    const int st = tid - 128;                  // 0..895
    float4 bs{}, fscc4{}, fsch4{};
    float c0 = 0.f;
    if (st < 512) {
      bs    = *(const float4*)(wsf + OFF_BSUM  + 4 * st);
      fscc4 = *(const float4*)(wsf + OFF_FSCC  + 4 * st);
      fsch4 = *(const float4*)(wsf + OFF_FSCHG + 4 * st);
    }
    for (int t = 0; t < T; ++t) {
      const int par = t & 1;
      const unsigned tg = (unsigned)(t + 1);
      spin_ge(&flg[FH], 2u * tg); __threadfence_block();
      // items: j<2048 gates-h (unit,kq); else cc: jj<512 -> m half (no wait), else cc half
#pragma unroll 1
      for (int it = 0; it < 4; ++it) {
        const int j = st + 896 * it;
        if (j >= 3072) break;
        if (j < 2048) {
          const int unit = j & 511, kq = j >> 9;
          const uint4* wp = (const uint4*)(wsu + OFF_WQH) + (size_t)(kq * 32) * 512 + unit;
          const unsigned* aw = hq_s + kq * 32;
          int4 acc{0, 0, 0, 0};
#pragma unroll 8
          for (int k = 0; k < 32; ++k) {
            const uint4 w = wp[(size_t)k * 512];
            const int a0 = (int)aw[k];
            acc.x = sdot4((int)w.x, a0, acc.x);
            acc.y = sdot4((int)w.y, a0, acc.y);
            acc.z = sdot4((int)w.z, a0, acc.z);
            acc.w = sdot4((int)w.w, a0, acc.w);
          }
          partH_s[kq][unit] = acc;
        } else {
          const int jj = j - 2048;
          const int unit = jj & 511;
          const int kh = 1 - (jj >> 9);        // first 512 items: m half (ready at step start)
          if (kh == 0) { spin_ge(&flg[FA], 2u * tg); __threadfence_block(); }
          const uint4* wp = (const uint4*)(wsu + OFF_WQCC) + (size_t)(kh * 32) * 512 + unit;
          const unsigned* aw = actq_s[par] + kh * 32;
          int4 acc{0, 0, 0, 0};
#pragma unroll 8
          for (int k = 0; k < 32; ++k) {
            const uint4 w = wp[(size_t)k * 512];
            const int a0 = (int)aw[k];
            acc.x = sdot4((int)w.x, a0, acc.x);
            acc.y = sdot4((int)w.y, a0, acc.y);
            acc.z = sdot4((int)w.z, a0, acc.z);
            acc.w = sdot4((int)w.w, a0, acc.w);
          }
          partC_s[kh][unit] = acc;
        }
      }
      __threadfence_block();
      if (!(tid & 63)) flag_add(&flg[FS]);
      spin_ge(&flg[FS], 14u * tg); __threadfence_block();

      // LSTM on stream waves 2-9 (st<512): c in regs, h to LDS
      if (st < 512) {
        const int4 p0 = partH_s[0][st], p1 = partH_s[1][st],
                   p2 = partH_s[2][st], p3 = partH_s[3][st];
        const int4 q0 = partC_s[0][st], q1 = partC_s[1][st];
        const float ai = bs.x + fscc4.x * (float)(q0.x + q1.x) + fsch4.x * (float)(p0.x + p1.x + p2.x + p3.x);
        const float af = bs.y + fscc4.y * (float)(q0.y + q1.y) + fsch4.y * (float)(p0.y + p1.y + p2.y + p3.y);
        const float ag = bs.z + fscc4.z * (float)(q0.z + q1.z) + fsch4.z * (float)(p0.z + p1.z + p2.z + p3.z);
        const float ao = bs.w + fscc4.w * (float)(q0.w + q1.w) + fsch4.w * (float)(p0.w + p1.w + p2.w + p3.w);
        const float ig = fast_sig(ai), fg = fast_sig(af);
        const float gg = fast_tanh(ag), og = fast_sig(ao);
        c0 = fg * c0 + ig * gg;
        h_s[st] = og * fast_tanh(c0);
        __threadfence_block();
        if (!(tid & 63)) flag_add(&flg[FL]);
      }
    }
  }
}

__global__ void finalize(const float* __restrict__ num, const float* __restrict__ den,
                         float* __restrict__ out) {
  __shared__ float red[2];
  const int t = threadIdx.x;     // 128 threads
  float v = num[t] / (den[t] + 1e-8f);
  v = wave_sum(v);
  if ((t & 63) == 0) red[t >> 6] = v;
  __syncthreads();
  if (t == 0) out[(size_t)B * T * F] = (red[0] + red[1]) / (float)T;
}

extern "C" void kernel_launch(void* const* d_in, const int* in_sizes, int n_in,
                              void* d_out, int out_size, void* d_ws, size_t ws_size,
                              hipStream_t stream) {
  const float* x      = (const float*)d_in[0];
  const float* m      = (const float*)d_in[1];
  const float* d      = (const float*)d_in[2];
  const float* tx     = (const float*)d_in[3];
  const float* tmask  = (const float*)d_in[4];
  const float* td_h_W = (const float*)d_in[5];
  const float* td_h_b = (const float*)d_in[6];
  const float* td_x_W = (const float*)d_in[7];
  const float* td_x_b = (const float*)d_in[8];
  const float* hist_W = (const float*)d_in[9];
  const float* hist_b = (const float*)d_in[10];
  const float* feat_W = (const float*)d_in[11];
  const float* feat_b = (const float*)d_in[12];
  const float* wc_W   = (const float*)d_in[13];
  const float* wc_b   = (const float*)d_in[14];
  const float* W_ih   = (const float*)d_in[15];
  const float* W_hh   = (const float*)d_in[16];
  const float* b_ih   = (const float*)d_in[17];
  const float* b_hh   = (const float*)d_in[18];

  float*    wsf = (float*)d_ws;
  unsigned* wsu = (unsigned*)d_ws;
  float*    out = (float*)d_out;

  if (ws_size < WS_WORDS * 4) return;   // OOB tripwire

  hipMemsetAsync(d_ws, 0, 256 * sizeof(float), stream);   // num/den
  prep_f16<<<dim3((59520 + 255) / 256), dim3(256), 0, stream>>>(
      td_h_W, feat_W, wc_W, b_ih, b_hh, wsu, wsf);
  prep_quant_wih<<<dim3(2048), dim3(64), 0, stream>>>(
      W_ih, wsu + OFF_WQCC, wsf + OFF_FSCC);
  prep_quant_whh<<<dim3(2048), dim3(128), 0, stream>>>(
      W_hh, wsu + OFF_WQH, wsf + OFF_FSCHG);
  prep_quant_hist<<<dim3(128), dim3(128), 0, stream>>>(
      hist_W, wsu + OFF_HISTQ, wsf + OFF_FSCH);
  rits_batch<<<dim3(NBLK), dim3(NTHR), 0, stream>>>(
      x, m, d, tx, tmask, td_h_b, td_x_W, td_x_b, hist_b, feat_b, wc_b,
      wsu, wsf, wsf + OFF_NUM, wsf + OFF_DEN, out);
  finalize<<<dim3(1), dim3(128), 0, stream>>>(wsf + OFF_NUM, wsf + OFF_DEN, out);
}